// Round 3
// baseline (257.599 us; speedup 1.0000x reference)
//
#include <hip/hip_runtime.h>
#include <hip/hip_bf16.h>
#include <stdint.h>

typedef unsigned short u16;
typedef __attribute__((ext_vector_type(4))) float f32x4;
typedef __attribute__((ext_vector_type(8))) __bf16 bf16x8;
typedef __attribute__((ext_vector_type(4))) unsigned int u32x4;

#define DEV __device__ __forceinline__

DEV u16 f2bf(float f){
  unsigned u = __builtin_bit_cast(unsigned, f);
  u += 0x7fffu + ((u >> 16) & 1u);
  return (u16)(u >> 16);
}

constexpr int Tt = 2048, Gg = 1024, HD = 64;
constexpr float LOG2E = 1.44269504088896340736f;

// ---------------- x -> bf16 ----------------
__global__ __launch_bounds__(256) void k_cvt_x(const float* __restrict__ x, u16* __restrict__ xb){
  long i = (long)blockIdx.x * 256 + threadIdx.x;   // 8 elems per thread
  const float4* p = (const float4*)x + 2 * i;
  float4 a = p[0], c = p[1];
  u32x4 v;
  v[0] = (unsigned)f2bf(a.x) | ((unsigned)f2bf(a.y) << 16);
  v[1] = (unsigned)f2bf(a.z) | ((unsigned)f2bf(a.w) << 16);
  v[2] = (unsigned)f2bf(c.x) | ((unsigned)f2bf(c.y) << 16);
  v[3] = (unsigned)f2bf(c.z) | ((unsigned)f2bf(c.w) << 16);
  *(u32x4*)(xb + 8 * i) = v;
}

// ---------------- weight transpose f32[k][n] -> bf16[n][k] ----------------
__global__ void k_transW(const float* __restrict__ wq, const float* __restrict__ wk,
                         const float* __restrict__ wv, const float* __restrict__ wp,
                         u16* __restrict__ wqkvT, u16* __restrict__ wpT){
  __shared__ float tile[32][33];
  int z = blockIdx.z;
  const float* w = (z == 0) ? wq : (z == 1) ? wk : (z == 2) ? wv : wp;
  u16* o = (z < 3) ? (wqkvT + (size_t)z * Gg * Gg) : wpT;
  int n0 = blockIdx.x * 32, k0 = blockIdx.y * 32;
  for (int r = threadIdx.y; r < 32; r += 8)
    tile[r][threadIdx.x] = w[(size_t)(k0 + r) * Gg + n0 + threadIdx.x];
  __syncthreads();
  for (int r = threadIdx.y; r < 32; r += 8)
    o[(size_t)(n0 + r) * Gg + k0 + threadIdx.x] = f2bf(tile[threadIdx.x][r]);
}

// ---------------- GEMM: C[M][N] = A[M][K](bf16) * Bt[N][K](bf16)^T ----------------
// EPI 0: QKV epilogue (bias, Q*0.125, scatter to [b][h][t][d] bf16)
// EPI 1: out proj epilogue (bias, f32 out)
template<int EPI>
__global__ __launch_bounds__(256) void k_gemm(
    const u16* __restrict__ A, const u16* __restrict__ Bt, int M, int N, int K,
    const float* __restrict__ b0, const float* __restrict__ b1, const float* __restrict__ b2,
    u16* __restrict__ q_out, u16* __restrict__ k_out, u16* __restrict__ v_out,
    float* __restrict__ out, const float* __restrict__ bp){
  __shared__ u16 lA[128 * 32];
  __shared__ u16 lB[128 * 32];
  const int tid = threadIdx.x;
  const int lane = tid & 63, w = tid >> 6;
  const int lr = lane & 15, lg = lane >> 4;
  const int wr = w >> 1, wc = w & 1;
  // XCD-aware bijective swizzle (gridDim.x % 8 == 0 for all our launches)
  int bid = blockIdx.x;
  int cpx = gridDim.x >> 3;
  int sbid = (bid & 7) * cpx + (bid >> 3);
  const int nbn = N >> 7;
  const int mb = sbid / nbn, nb = sbid % nbn;
  const int m0 = mb * 128, n0 = nb * 128;

  f32x4 acc[4][4];
#pragma unroll
  for (int i = 0; i < 4; i++)
#pragma unroll
    for (int j = 0; j < 4; j++) acc[i][j] = (f32x4)0.f;

  const int srow = tid >> 1;        // 0..127
  const int scb = (tid & 1) * 2;    // chunk base 0 or 2
  const int swz = (srow >> 2) & 3;
  const size_t aRow = (size_t)(m0 + srow) * K;
  const size_t bRow = (size_t)(n0 + srow) * K;

  for (int k0 = 0; k0 < K; k0 += 32) {
    __syncthreads();
#pragma unroll
    for (int c = 0; c < 2; c++) {
      int ch = scb + c;
      u32x4 va = *(const u32x4*)(A + aRow + k0 + ch * 8);
      u32x4 vb = *(const u32x4*)(Bt + bRow + k0 + ch * 8);
      int chs = ch ^ swz;
      *(u32x4*)&lA[srow * 32 + chs * 8] = va;
      *(u32x4*)&lB[srow * 32 + chs * 8] = vb;
    }
    __syncthreads();
    bf16x8 af[4], bfr[4];
#pragma unroll
    for (int mi = 0; mi < 4; mi++) {
      int row = wr * 64 + mi * 16 + lr;
      int ch = lg ^ ((row >> 2) & 3);
      af[mi] = *(const bf16x8*)&lA[row * 32 + ch * 8];
    }
#pragma unroll
    for (int nj = 0; nj < 4; nj++) {
      int row = wc * 64 + nj * 16 + lr;
      int ch = lg ^ ((row >> 2) & 3);
      bfr[nj] = *(const bf16x8*)&lB[row * 32 + ch * 8];
    }
#pragma unroll
    for (int mi = 0; mi < 4; mi++)
#pragma unroll
      for (int nj = 0; nj < 4; nj++)
        acc[mi][nj] = __builtin_amdgcn_mfma_f32_16x16x32_bf16(af[mi], bfr[nj], acc[mi][nj], 0, 0, 0);
  }

  if constexpr (EPI == 0) {
#pragma unroll
    for (int nj = 0; nj < 4; nj++) {
      int col = n0 + wc * 64 + nj * 16 + lr;     // 0..3071
      int tsel = col >> 10;
      int nn = col & 1023;
      const float* bptr = (tsel == 0) ? b0 : (tsel == 1) ? b1 : b2;
      float bias = bptr[nn];
      u16* dst = (tsel == 0) ? q_out : (tsel == 1) ? k_out : v_out;
      int h = nn >> 6, d = nn & 63;
#pragma unroll
      for (int mi = 0; mi < 4; mi++) {
        int rowb = m0 + wr * 64 + mi * 16 + lg * 4;
#pragma unroll
        for (int r = 0; r < 4; r++) {
          int row = rowb + r;                    // token index
          int bb = row >> 11, t = row & 2047;
          float v = acc[mi][nj][r] + bias;
          if (tsel == 0) v *= 0.125f;            // fold 1/sqrt(HD)
          dst[((size_t)(bb * 16 + h) * 2048 + t) * 64 + d] = f2bf(v);
        }
      }
    }
  } else {
#pragma unroll
    for (int nj = 0; nj < 4; nj++) {
      int col = n0 + wc * 64 + nj * 16 + lr;
      float bias = bp[col];
#pragma unroll
      for (int mi = 0; mi < 4; mi++) {
#pragma unroll
        for (int r = 0; r < 4; r++) {
          int row = m0 + wr * 64 + mi * 16 + lg * 4 + r;
          out[(size_t)row * 1024 + col] = acc[mi][nj][r] + bias;
        }
      }
    }
  }
}

// ---------------- causal flash attention ----------------
// Q,K,V bf16 [b*h][T][64]; O bf16 [b][t][h*64+d]. Q pre-scaled by 0.125.
__global__ __launch_bounds__(256) void k_attn(const u16* __restrict__ Qb, const u16* __restrict__ Kb,
                                              const u16* __restrict__ Vb, u16* __restrict__ Ob){
  __shared__ u16 vt[64 * 32];        // V^T tile [d][kv], swizzled 64B rows
  __shared__ u16 plds[4][1024];      // per-wave P [32][32], swizzled
  const int tid = threadIdx.x, lane = tid & 63, w = tid >> 6;
  const int lr = lane & 15, lg = lane >> 4;
  const int bh = blockIdx.x & 63;
  const int qb = 15 - (blockIdx.x >> 6);   // heavy blocks first
  const int q0 = qb * 128, q0w = q0 + w * 32;
  const int b = bh >> 4, h = bh & 15;
  const size_t base = (size_t)bh * Tt * HD;

  bf16x8 qf[2][2];
#pragma unroll
  for (int qg = 0; qg < 2; qg++)
#pragma unroll
    for (int dh = 0; dh < 2; dh++)
      qf[qg][dh] = *(const bf16x8*)(Qb + base + (size_t)(q0w + qg * 16 + lr) * 64 + dh * 32 + lg * 8);

  f32x4 Oacc[2][4];
#pragma unroll
  for (int qg = 0; qg < 2; qg++)
#pragma unroll
    for (int nf = 0; nf < 4; nf++) Oacc[qg][nf] = (f32x4)0.f;
  float mrun[2] = {-__builtin_inff(), -__builtin_inff()};
  float lsum[2] = {0.f, 0.f};

  const int nt = (q0 + 128) >> 5;
  for (int kt = 0; kt < nt; kt++) {
    const int kv0 = kt << 5;
    __syncthreads();
    { // stage V^T (swizzled): thread -> V[kv0+kv][d0..d0+7]
      int kv = tid >> 3, d0 = (tid & 7) * 8;
      u32x4 vv = *(const u32x4*)(Vb + base + (size_t)(kv0 + kv) * 64 + d0);
#pragma unroll
      for (int j = 0; j < 4; j++) {
        unsigned pr = vv[j];
        int dA = d0 + 2 * j, dB = dA + 1;
        vt[dA * 32 + (((kv >> 3) ^ ((dA >> 2) & 3)) << 3) + (kv & 7)] = (u16)pr;
        vt[dB * 32 + (((kv >> 3) ^ ((dB >> 2) & 3)) << 3) + (kv & 7)] = (u16)(pr >> 16);
      }
    }
    __syncthreads();
    if (kv0 > q0w + 31) continue;   // fully masked for this wave

    // S^T = K * Q^T  (row=kv, col=q)
    f32x4 accs[2][2];
#pragma unroll
    for (int kg = 0; kg < 2; kg++)
#pragma unroll
      for (int qg = 0; qg < 2; qg++) accs[kg][qg] = (f32x4)0.f;
    bf16x8 kf[2][2];
#pragma unroll
    for (int kg = 0; kg < 2; kg++)
#pragma unroll
      for (int dh = 0; dh < 2; dh++)
        kf[kg][dh] = *(const bf16x8*)(Kb + base + (size_t)(kv0 + kg * 16 + lr) * 64 + dh * 32 + lg * 8);
#pragma unroll
    for (int kg = 0; kg < 2; kg++)
#pragma unroll
      for (int qg = 0; qg < 2; qg++)
#pragma unroll
        for (int dh = 0; dh < 2; dh++)
          accs[kg][qg] = __builtin_amdgcn_mfma_f32_16x16x32_bf16(kf[kg][dh], qf[qg][dh], accs[kg][qg], 0, 0, 0);

    const bool full = (kv0 + 31 <= q0w);
#pragma unroll
    for (int qg = 0; qg < 2; qg++) {
      int q = q0w + qg * 16 + lr;
      float pv[2][4];
      float tm = -__builtin_inff();
#pragma unroll
      for (int kg = 0; kg < 2; kg++)
#pragma unroll
        for (int r = 0; r < 4; r++) {
          float s = accs[kg][qg][r];
          if (!full) { int kv = kv0 + kg * 16 + lg * 4 + r; if (kv > q) s = -__builtin_inff(); }
          pv[kg][r] = s;
          tm = fmaxf(tm, s);
        }
      tm = fmaxf(tm, __shfl_xor(tm, 16));
      tm = fmaxf(tm, __shfl_xor(tm, 32));
      float mnew = fmaxf(mrun[qg], tm);
      float alpha = exp2f((mrun[qg] - mnew) * LOG2E);
      mrun[qg] = mnew;
      float ps = 0.f;
#pragma unroll
      for (int kg = 0; kg < 2; kg++)
#pragma unroll
        for (int r = 0; r < 4; r++) {
          float p = exp2f((pv[kg][r] - mnew) * LOG2E);
          pv[kg][r] = p;
          ps += p;
        }
      ps += __shfl_xor(ps, 16);
      ps += __shfl_xor(ps, 32);
      lsum[qg] = lsum[qg] * alpha + ps;

      // write P (bf16, packed pairs) to per-wave LDS, swizzled [q][kv]
      int prow = qg * 16 + lr;
      int psw = (prow >> 2) & 3;
#pragma unroll
      for (int kg = 0; kg < 2; kg++)
#pragma unroll
        for (int p2 = 0; p2 < 2; p2++) {
          unsigned pk = (unsigned)f2bf(pv[kg][2 * p2]) | ((unsigned)f2bf(pv[kg][2 * p2 + 1]) << 16);
          int chunk = kg * 2 + (lg >> 1);
          int off = prow * 32 + ((chunk ^ psw) << 3) + ((lg & 1) << 2) + 2 * p2;
          *(unsigned*)&plds[w][off] = pk;
        }
      // rescale O (O rows live at q = 4*lg + r within the 16-block)
#pragma unroll
      for (int r = 0; r < 4; r++) {
        float aO = __shfl(alpha, lg * 4 + r);
#pragma unroll
        for (int nf = 0; nf < 4; nf++) Oacc[qg][nf][r] *= aO;
      }
    }

    // O += P * V
    bf16x8 vfr[4];
#pragma unroll
    for (int nf = 0; nf < 4; nf++) {
      int d = nf * 16 + lr;
      vfr[nf] = *(const bf16x8*)&vt[d * 32 + ((lg ^ ((d >> 2) & 3)) << 3)];
    }
#pragma unroll
    for (int qg = 0; qg < 2; qg++) {
      int prow = qg * 16 + lr;
      bf16x8 pf = *(const bf16x8*)&plds[w][prow * 32 + ((lg ^ ((prow >> 2) & 3)) << 3)];
#pragma unroll
      for (int nf = 0; nf < 4; nf++)
        Oacc[qg][nf] = __builtin_amdgcn_mfma_f32_16x16x32_bf16(pf, vfr[nf], Oacc[qg][nf], 0, 0, 0);
    }
  }

  // finalize: O /= lsum, write [b][t][h*64+d]
#pragma unroll
  for (int qg = 0; qg < 2; qg++) {
    float li = 1.f / lsum[qg];
#pragma unroll
    for (int r = 0; r < 4; r++) {
      float liO = __shfl(li, lg * 4 + r);
      int q = q0w + qg * 16 + lg * 4 + r;
      size_t rowoff = ((size_t)b * Tt + q) * Gg + h * 64;
#pragma unroll
      for (int nf = 0; nf < 4; nf++)
        Ob[rowoff + nf * 16 + lr] = f2bf(Oacc[qg][nf][r] * liO);
    }
  }
}

extern "C" void kernel_launch(void* const* d_in, const int* in_sizes, int n_in,
                              void* d_out, int out_size, void* d_ws, size_t ws_size,
                              hipStream_t stream){
  const float* x  = (const float*)d_in[0];
  const float* wq = (const float*)d_in[1];
  const float* bq = (const float*)d_in[2];
  const float* wk = (const float*)d_in[3];
  const float* bk = (const float*)d_in[4];
  const float* wv = (const float*)d_in[5];
  const float* bv = (const float*)d_in[6];
  const float* wp = (const float*)d_in[7];
  const float* bp = (const float*)d_in[8];
  float* out = (float*)d_out;
  char* ws = (char*)d_ws;

  u16* xb    = (u16*)(ws);                  // 16 MB  (8192x1024 bf16)
  u16* wqkvT = (u16*)(ws + (16l << 20));    // 6 MB   ([3072][1024] bf16)
  u16* wpT   = (u16*)(ws + (22l << 20));    // 2 MB
  u16* Qb    = (u16*)(ws + (24l << 20));    // 16 MB  ([64][2048][64] bf16)
  u16* Kb    = (u16*)(ws + (40l << 20));    // 16 MB
  u16* Vb    = (u16*)(ws + (56l << 20));    // 16 MB
  u16* Ao    = (u16*)(ws + (72l << 20));    // 16 MB  ([8192][1024] bf16)

  k_cvt_x<<<dim3(4096), dim3(256), 0, stream>>>(x, xb);
  k_transW<<<dim3(32, 32, 4), dim3(32, 8), 0, stream>>>(wq, wk, wv, wp, wqkvT, wpT);
  k_gemm<0><<<dim3(64 * 24), dim3(256), 0, stream>>>(xb, wqkvT, 8192, 3072, 1024,
                                                     bq, bk, bv, Qb, Kb, Vb, nullptr, nullptr);
  k_attn<<<dim3(1024), dim3(256), 0, stream>>>(Qb, Kb, Vb, Ao);
  k_gemm<1><<<dim3(64 * 8), dim3(256), 0, stream>>>(Ao, wpT, 8192, 1024, 1024,
                                                    nullptr, nullptr, nullptr, nullptr, nullptr, nullptr,
                                                    out, bp);
}